// Round 9
// baseline (173.405 us; speedup 1.0000x reference)
//
#include <hip/hip_runtime.h>

typedef unsigned short us;
typedef unsigned int uns;
typedef __attribute__((ext_vector_type(8))) short short8;
typedef __attribute__((ext_vector_type(4))) float floatx4;
typedef __attribute__((ext_vector_type(16))) float floatx16;
typedef __attribute__((ext_vector_type(4))) uns unsx4;

__device__ __forceinline__ us f2b(float f) {
    union { float f; unsigned u; } x; x.f = f;
    unsigned r = x.u + 0x7fffu + ((x.u >> 16) & 1u);
    return (us)(r >> 16);
}
__device__ __forceinline__ uns fbits(float f) {
    union { float f; unsigned u; } x; x.f = f; return x.u;
}
// rounded pack (epilogues)
__device__ __forceinline__ uns pk2(float hi, float lo) {
    return __builtin_amdgcn_perm(fbits(hi) + 0x8000u, fbits(lo) + 0x8000u, 0x07060302u);
}
// truncating pack (hot loop: 1 instr; bias cancels in num/den ratio)
__device__ __forceinline__ uns pk2t(float hi, float lo) {
    return __builtin_amdgcn_perm(fbits(hi), fbits(lo), 0x07060302u);
}
// raw v_exp_f32: no denormal-guard expansion (HW flush-to-zero is what
// softmax wants).
__device__ __forceinline__ float ex2(float x) {
    return __builtin_amdgcn_exp2f(x);
}

#define C_DIM 256
#define N_DIM 4096
#define CN (C_DIM * N_DIM)   // 1048576 per batch
#define CSC (0.17677669529663687f * 1.4426950408889634f)   // 1/sqrt(32)*log2e

// ============================================= K1: GN partials + weight prep
__global__ __launch_bounds__(256) void k_part_prep(
        const float* __restrict__ x, float* __restrict__ part,
        const float* __restrict__ Wq, const float* __restrict__ Wk,
        const float* __restrict__ Wv, const float* __restrict__ Wo,
        const float* __restrict__ bq, const float* __restrict__ bk,
        const float* __restrict__ bv, const float* __restrict__ bo,
        us* __restrict__ Wb, float* __restrict__ bst) {
    const int t = threadIdx.x;
    if (blockIdx.y == 16) {   // prep blocks: fold CSC into Wq/bq
        const int xb = blockIdx.x;
#pragma unroll
        for (int e = 0; e < 4; ++e) {
            int id = e * 16384 + xb * 256 + t;
            Wb[id]          = f2b(Wq[id] * CSC);
            Wb[65536 + id]  = f2b(Wk[id]);
            Wb[131072 + id] = f2b(Wv[id]);
            Wb[196608 + id] = f2b(Wo[id]);
        }
        if (xb == 0) {
            bst[t]       = bq[t] * CSC;
            bst[256 + t] = bk[t];
            bst[512 + t] = bv[t];
            bst[768 + t] = bo[t];
        }
        return;
    }
    const int bg = blockIdx.y, sl = blockIdx.x;
    const float* base = x + (size_t)bg * 131072 + (size_t)sl * 2048 + t * 8;
    float4 a = *(const float4*)base;
    float4 b = *(const float4*)(base + 4);
    float s  = a.x + a.y + a.z + a.w + b.x + b.y + b.z + b.w;
    float ss = a.x*a.x + a.y*a.y + a.z*a.z + a.w*a.w
             + b.x*b.x + b.y*b.y + b.z*b.z + b.w*b.w;
    __shared__ float r1[256], r2[256];
    r1[t] = s; r2[t] = ss;
    __syncthreads();
    for (int off = 128; off > 0; off >>= 1) {
        if (t < off) { r1[t] += r1[t + off]; r2[t] += r2[t + off]; }
        __syncthreads();
    }
    if (t == 0) {
        part[(bg * 64 + sl) * 2]     = r1[0];
        part[(bg * 64 + sl) * 2 + 1] = r2[0];
    }
}

// ============================================= K2: normalize -> XT[z][n][c]
// R7-verified: 1024 blocks (4 waves/SIMD) vs 256 saved ~8 us.
__global__ __launch_bounds__(256) void k_gn_normT(const float* __restrict__ x,
                                                  const float* __restrict__ gamma,
                                                  const float* __restrict__ beta,
                                                  const float* __restrict__ part,
                                                  us* __restrict__ XT) {
    const int t = threadIdx.x, g = blockIdx.y, z = blockIdx.z;
    const int nb = blockIdx.x & 15, c8 = blockIdx.x >> 4;
    const int bg = z * 8 + g;
    __shared__ float scs[32], offs[32], mv[2];
    if (t < 64) {
        float s  = part[(bg * 64 + t) * 2];
        float ss = part[(bg * 64 + t) * 2 + 1];
#pragma unroll
        for (int off = 1; off < 64; off <<= 1) {
            s  += __shfl_xor(s, off, 64);
            ss += __shfl_xor(ss, off, 64);
        }
        if (t == 0) {
            const float inv = 1.f / 131072.f;
            float mean = s * inv;
            float var  = ss * inv - mean * mean;
            mv[0] = mean; mv[1] = rsqrtf(var + 1e-5f);
        }
    }
    __syncthreads();
    if (t < 32) {
        float sc = mv[1] * gamma[g * 32 + t];
        scs[t]  = sc;
        offs[t] = beta[g * 32 + t] - mv[0] * sc;
    }
    __syncthreads();
    const int n = nb * 256 + t;
    const float* xp = x + ((size_t)z * 256 + g * 32) * N_DIM + n;
    us* op = XT + ((size_t)z * N_DIM + n) * 256 + g * 32;
    short8 o;
#pragma unroll
    for (int i = 0; i < 8; ++i) {
        int c = c8 * 8 + i;
        float v = xp[(size_t)c * N_DIM];
        o[i] = (short)f2b(v * scs[c] + offs[c]);
    }
    *(short8*)(op + c8 * 8) = o;
}

// ============================================= K3: QKV GEMM (no LDS/barriers)
__global__ __launch_bounds__(256) void k_qkv(const us* __restrict__ W,
                                             const float* __restrict__ bias,
                                             const us* __restrict__ XT,
                                             us* __restrict__ QT,
                                             us* __restrict__ KTg,
                                             us* __restrict__ Vb) {
    const int t = threadIdx.x;
    const int n0 = blockIdx.x * 64, m0 = blockIdx.y * 64, z = blockIdx.z;
    const int l = t & 63, w = t >> 6, l15 = l & 15, quad = l >> 4;
    const int wm = m0 + (w >> 1) * 32, wn = n0 + (w & 1) * 32;
    const us* Ap = W + (size_t)(wm + l15) * 256 + quad * 8;
    const us* Bp = XT + ((size_t)z * N_DIM + wn + l15) * 256 + quad * 8;

    floatx4 acc[2][2] = {};
#pragma unroll
    for (int k0 = 0; k0 < 256; k0 += 32) {
        short8 a0 = *(const short8*)(Ap + k0);
        short8 a1 = *(const short8*)(Ap + k0 + 16 * 256);
        short8 b0 = *(const short8*)(Bp + k0);
        short8 b1 = *(const short8*)(Bp + k0 + 16 * 256);
        acc[0][0] = __builtin_amdgcn_mfma_f32_16x16x32_bf16(a0, b0, acc[0][0], 0, 0, 0);
        acc[0][1] = __builtin_amdgcn_mfma_f32_16x16x32_bf16(a0, b1, acc[0][1], 0, 0, 0);
        acc[1][0] = __builtin_amdgcn_mfma_f32_16x16x32_bf16(a1, b0, acc[1][0], 0, 0, 0);
        acc[1][1] = __builtin_amdgcn_mfma_f32_16x16x32_bf16(a1, b1, acc[1][1], 0, 0, 0);
    }

    if (blockIdx.y < 8) {   // Q or K: packed-transposed [bh][n][32] stores
        us* Dst = (blockIdx.y < 4) ? QT : KTg;
        const int h = (wm >> 5) & 7, bh = z * 8 + h;
#pragma unroll
        for (int mt = 0; mt < 2; ++mt) {
            const int d0 = mt * 16 + quad * 4;
            float b0v = bias[wm + mt * 16 + quad * 4 + 0];
            float b1v = bias[wm + mt * 16 + quad * 4 + 1];
            float b2v = bias[wm + mt * 16 + quad * 4 + 2];
            float b3v = bias[wm + mt * 16 + quad * 4 + 3];
#pragma unroll
            for (int nt = 0; nt < 2; ++nt) {
                int col = wn + nt * 16 + l15;
                uint2 pw;
                pw.x = pk2(acc[mt][nt][1] + b1v, acc[mt][nt][0] + b0v);
                pw.y = pk2(acc[mt][nt][3] + b3v, acc[mt][nt][2] + b2v);
                *(uint2*)(Dst + ((size_t)bh * N_DIM + col) * 32 + d0) = pw;
            }
        }
    } else {                // V rows: natural [c][n]
#pragma unroll
        for (int mt = 0; mt < 2; ++mt)
#pragma unroll
            for (int nt = 0; nt < 2; ++nt)
#pragma unroll
                for (int r = 0; r < 4; ++r) {
                    int row = wm + mt * 16 + quad * 4 + r;
                    int col = wn + nt * 16 + l15;
                    Vb[((size_t)z * 256 + (row - 512)) * N_DIM + col] =
                        f2b(acc[mt][nt][r] + bias[row]);
                }
    }
}

// ============================================= K4: attention
// Block = 1024 threads = 16 waves = 4 q-tiles(32q) x 4 key-quarters(1024).
// R8 ledger: VGPR=60 allows 8 waves/SIMD but 512-thr blocks only gave 4.
// 4-way key-split doubles resident waves (2 blocks/CU x 16 waves) at
// UNCHANGED global traffic and byte-identical per-iter math -- more waves
// to hide the serial QK->exp->permlane->PV chain (the R6-measured stall).
// R7 lesson stands: do NOT add VGPRs; this uses occupancy instead.
// Fixed-max softmax => partials are plain sums; 4 partials per q-tile
// combine via LDS scratch (60 KB, reuses staging buffers).
__device__ __forceinline__ floatx16 mfma32(short8 a, short8 b, floatx16 c) {
    return __builtin_amdgcn_mfma_f32_32x32x16_bf16(a, b, c, 0, 0, 0);
}
// exp2 + truncate-pack one 32-key tile's scores, then half-swap into the
// two k=16 B-fragments (v_permlane32_swap_b32: vdst.hi <-> vsrc.lo).
__device__ __forceinline__ void mkfrag(const floatx16& s, short8& p1, short8& p2) {
    uns d0 = pk2t(ex2(s[1]),  ex2(s[0]));
    uns d1 = pk2t(ex2(s[3]),  ex2(s[2]));
    uns d2 = pk2t(ex2(s[5]),  ex2(s[4]));
    uns d3 = pk2t(ex2(s[7]),  ex2(s[6]));
    uns d4 = pk2t(ex2(s[9]),  ex2(s[8]));
    uns d5 = pk2t(ex2(s[11]), ex2(s[10]));
    uns d6 = pk2t(ex2(s[13]), ex2(s[12]));
    uns d7 = pk2t(ex2(s[15]), ex2(s[14]));
    asm volatile("v_permlane32_swap_b32 %0, %1" : "+v"(d0), "+v"(d2));
    asm volatile("v_permlane32_swap_b32 %0, %1" : "+v"(d1), "+v"(d3));
    asm volatile("v_permlane32_swap_b32 %0, %1" : "+v"(d4), "+v"(d6));
    asm volatile("v_permlane32_swap_b32 %0, %1" : "+v"(d5), "+v"(d7));
    unsx4 u1 = {d0, d1, d2, d3};
    unsx4 u2 = {d4, d5, d6, d7};
    p1 = __builtin_bit_cast(short8, u1);
    p2 = __builtin_bit_cast(short8, u2);
}

__global__ __launch_bounds__(1024, 4) void k_attn(const us* __restrict__ QT,
                                                  const us* __restrict__ KTg,
                                                  const us* __restrict__ Vb,
                                                  us* __restrict__ AOT) {
    // layout: K quarter-tiles [buf][kh] at 0, V quarter-tiles at +16384 us
    __shared__ __attribute__((aligned(16))) us SM[32768];   // 64 KB
    us* Kbase = SM;
    us* Vbase = SM + 16384;
    const int t = threadIdx.x;
    const int l = t & 63, w = t >> 6, hf = l >> 5, k31 = l & 31;
    const int sw = w & 3, kh = w >> 2;          // q-tile role, key-quarter role
    const int bh = blockIdx.y, z = bh >> 3, hd = bh & 7;
    const us* KTp = KTg + (size_t)bh * N_DIM * 32;
    const us* Vp  = Vb  + ((size_t)z * 256 + hd * 32) * N_DIM;
    const int q0 = blockIdx.x * 128 + sw * 32;

    // Q B-frags: n=q=lane&31, k=d=8*hf+j (bq1: d 0-15, bq2: d 16-31)
    const us* qb = QT + ((size_t)bh * N_DIM + q0 + k31) * 32 + hf * 8;
    short8 bq1 = *(const short8*)qb;
    short8 bq2 = *(const short8*)(qb + 16);
    short8 ones;
#pragma unroll
    for (int j = 0; j < 8; ++j) ones[j] = (short)0x3F80;   // bf16 1.0

    floatx16 o  = (floatx16)0.0f;
    floatx16 dn = (floatx16)0.0f;

    // ---- cooperative staging: the 4 sw-waves of each kh stage its tile ----
    const int krow = sw * 16 + (l >> 2), kslot = l & 3;
    const int kxs  = kslot ^ ((l >> 3) & 3);          // == kslot ^ ((krow>>1)&3)
    const us* kgs  = KTp + (size_t)(kh * 1024 + krow) * 32 + kslot * 8;
    us*       kds  = Kbase + kh * 2048 + krow * 32 + kxs * 8;
    const int vrow = sw * 8 + (l >> 3), vslot = l & 7;
    const int vxs  = vslot ^ ((l >> 3) & 7);          // == vslot ^ (vrow&7)
    const us* vgs  = Vp + (size_t)vrow * N_DIM + kh * 1024 + vslot * 8;
    us*       vds  = Vbase + kh * 2048 + vrow * 64 + vxs * 8;

    // ---- swizzled frag-read pointers (own quarter slice) ----
    const int kf = (k31 >> 1) & 3;
    const us* ka0p = Kbase + kh * 2048 + k31 * 32 + ((hf)     ^ kf) * 8;
    const us* ka1p = Kbase + kh * 2048 + k31 * 32 + ((2 + hf) ^ kf) * 8;
    const int vf = k31 & 7;
    const us* vp0 = Vbase + kh * 2048 + k31 * 64 + ((0 + hf) ^ vf) * 8;
    const us* vp1 = Vbase + kh * 2048 + k31 * 64 + ((2 + hf) ^ vf) * 8;
    const us* vp2 = Vbase + kh * 2048 + k31 * 64 + ((4 + hf) ^ vf) * 8;
    const us* vp3 = Vbase + kh * 2048 + k31 * 64 + ((6 + hf) ^ vf) * 8;

    // prologue: stage tile 0 into buf 0
    {
        int4 gk = *(const int4*)kgs;
        int4 gv = *(const int4*)vgs;
        *(int4*)kds = gk;
        *(int4*)vds = gv;
    }
    __syncthreads();
    int cur = 0;

    for (int m0 = 0; m0 < 1024; m0 += 64) {
        // issue next-tile global loads (consumed by ds_write at loop tail)
        const int mnext = (m0 + 64) & 1023;
        int4 ngk = *(const int4*)(kgs + (size_t)mnext * 32);
        int4 ngv = *(const int4*)(vgs + mnext);

        const int bo = cur * 8192;           // [buf] stride = 4 quarter-tiles
        short8 ka0 = *(const short8*)(ka0p + bo);          // keys 0-31, d 0-15
        short8 ka1 = *(const short8*)(ka1p + bo);          // keys 0-31, d 16-31
        short8 kb0 = *(const short8*)(ka0p + bo + 1024);   // keys 32-63
        short8 kb1 = *(const short8*)(ka1p + bo + 1024);
        short8 v0  = *(const short8*)(vp0 + bo);           // keys  0-15
        short8 v1  = *(const short8*)(vp1 + bo);           // keys 16-31
        short8 v2  = *(const short8*)(vp2 + bo);           // keys 32-47
        short8 v3  = *(const short8*)(vp3 + bo);           // keys 48-63

        floatx16 s0 = (floatx16)0.0f, s1 = (floatx16)0.0f;
        s0 = mfma32(ka0, bq1, s0);
        s0 = mfma32(ka1, bq2, s0);
        s1 = mfma32(kb0, bq1, s1);
        s1 = mfma32(kb1, bq2, s1);

        short8 p1, p2, p3, p4;
        mkfrag(s0, p1, p2);
        mkfrag(s1, p3, p4);

        o  = mfma32(v0, p1, o);   dn = mfma32(ones, p1, dn);
        o  = mfma32(v1, p2, o);   dn = mfma32(ones, p2, dn);
        o  = mfma32(v2, p3, o);   dn = mfma32(ones, p3, dn);
        o  = mfma32(v3, p4, o);   dn = mfma32(ones, p4, dn);

        // write staged tile into buf[cur^1]; barrier publishes it
        *(int4*)(kds + (cur ^ 1) * 8192) = ngk;
        *(int4*)(vds + (cur ^ 1) * 8192) = ngv;
        __syncthreads();
        cur ^= 1;
    }

    // -------- combine key-quarter partials: waves (sw, sw+4, sw+8, sw+12) --
    // scratch reuses SM (60 KB of 64 KB); stride 20 dwords (16B-aligned).
    float* sc = (float*)SM;
    if (kh) {
        float* dst = sc + (size_t)((kh - 1) * 256 + sw * 64 + l) * 20;
        *(floatx4*)(dst + 0)  = ((const floatx4*)&o)[0];
        *(floatx4*)(dst + 4)  = ((const floatx4*)&o)[1];
        *(floatx4*)(dst + 8)  = ((const floatx4*)&o)[2];
        *(floatx4*)(dst + 12) = ((const floatx4*)&o)[3];
        dst[16] = dn[0];
    }
    __syncthreads();
    if (kh == 0) {
        float dtot = dn[0];
        float ov[16];
#pragma unroll
        for (int i = 0; i < 16; ++i) ov[i] = o[i];
#pragma unroll
        for (int s = 0; s < 3; ++s) {
            const float* src = sc + (size_t)(s * 256 + sw * 64 + l) * 20;
            floatx4 a0 = *(const floatx4*)(src + 0);
            floatx4 a1 = *(const floatx4*)(src + 4);
            floatx4 a2 = *(const floatx4*)(src + 8);
            floatx4 a3 = *(const floatx4*)(src + 12);
#pragma unroll
            for (int i = 0; i < 4; ++i) {
                ov[i]      += a0[i];
                ov[4 + i]  += a1[i];
                ov[8 + i]  += a2[i];
                ov[12 + i] += a3[i];
            }
            dtot += src[16];
        }

        // O[d][q]: d=(reg&3)+8*(reg>>2)+4*hf, q=q0+k31
        const float inv = 1.f / dtot;
        const int q = q0 + k31;
        us* op = AOT + ((size_t)z * N_DIM + q) * 256 + hd * 32 + hf * 4;
#pragma unroll
        for (int g = 0; g < 4; ++g) {
            uint2 u;
            u.x = pk2(ov[4 * g + 1] * inv, ov[4 * g + 0] * inv);
            u.y = pk2(ov[4 * g + 3] * inv, ov[4 * g + 2] * inv);
            *(uint2*)(op + 8 * g) = u;
        }
    }
}

// ============================================= K5: output GEMM (fp32 + resid)
// R8 lesson class (K2/R7): 512 blocks = 2 waves/SIMD was latency-starved.
// Finer tiling: per-wave 16m x 32n, grid y 4->8 => 4096 waves = 4/SIMD.
__global__ __launch_bounds__(256) void k_out(const us* __restrict__ W,
                                             const float* __restrict__ bias,
                                             const us* __restrict__ AOT,
                                             float* __restrict__ Out,
                                             const float* __restrict__ resid) {
    const int t = threadIdx.x;
    const int n0 = blockIdx.x * 64, m0 = blockIdx.y * 32, z = blockIdx.z;
    const int l = t & 63, w = t >> 6, l15 = l & 15, quad = l >> 4;
    const int wm = m0 + (w >> 1) * 16, wn = n0 + (w & 1) * 32;
    const us* Ap = W + (size_t)(wm + l15) * 256 + quad * 8;
    const us* Bp = AOT + ((size_t)z * N_DIM + wn + l15) * 256 + quad * 8;

    floatx4 acc[2] = {};
#pragma unroll
    for (int k0 = 0; k0 < 256; k0 += 32) {
        short8 a0 = *(const short8*)(Ap + k0);
        short8 b0 = *(const short8*)(Bp + k0);
        short8 b1 = *(const short8*)(Bp + k0 + 16 * 256);
        acc[0] = __builtin_amdgcn_mfma_f32_16x16x32_bf16(a0, b0, acc[0], 0, 0, 0);
        acc[1] = __builtin_amdgcn_mfma_f32_16x16x32_bf16(a0, b1, acc[1], 0, 0, 0);
    }

#pragma unroll
    for (int nt = 0; nt < 2; ++nt)
#pragma unroll
        for (int r = 0; r < 4; ++r) {
            int row = wm + quad * 4 + r;
            int col = wn + nt * 16 + l15;
            size_t oidx = ((size_t)z * 256 + row) * N_DIM + col;
            Out[oidx] = acc[nt][r] + bias[row] + resid[oidx];
        }
}

// ============================================= launch
extern "C" void kernel_launch(void* const* d_in, const int* in_sizes, int n_in,
                              void* d_out, int out_size, void* d_ws, size_t ws_size,
                              hipStream_t stream) {
    (void)in_sizes; (void)n_in; (void)out_size; (void)ws_size;
    const float* x     = (const float*)d_in[0];
    const float* gamma = (const float*)d_in[1];
    const float* beta  = (const float*)d_in[2];
    const float* Wq = (const float*)d_in[3]; const float* bq = (const float*)d_in[4];
    const float* Wk = (const float*)d_in[5]; const float* bk = (const float*)d_in[6];
    const float* Wv = (const float*)d_in[7]; const float* bv = (const float*)d_in[8];
    const float* Wo = (const float*)d_in[9]; const float* bo = (const float*)d_in[10];

    float* part = (float*)d_ws;                                  // 2048 f
    us*    Wb   = (us*)((char*)d_ws + 16384);                    // 512 KB
    float* bst  = (float*)((char*)d_ws + 16384 + 524288);        // 4 KB
    us*    XT   = (us*)((char*)d_ws + 16384 + 524288 + 4096);    // 4 MB
    us*    QT   = XT + 2 * CN;                                   // [16][4096][32] 4 MB
    us*    AOT  = QT + 2 * CN;                                   // 4 MB
    us*    Vb   = (us*)d_out;                                    // d_out front 4 MB
    us*    KTg  = (us*)d_out + 2 * CN;                           // d_out back 4 MB

    k_part_prep<<<dim3(64, 17), dim3(256), 0, stream>>>(x, part, Wq, Wk, Wv, Wo,
                                                        bq, bk, bv, bo, Wb, bst);
    k_gn_normT<<<dim3(64, 8, 2), dim3(256), 0, stream>>>(x, gamma, beta, part, XT);
    k_qkv<<<dim3(64, 12, 2), dim3(256), 0, stream>>>(Wb, bst, XT, QT, KTg, Vb);
    k_attn<<<dim3(32, 16), dim3(1024), 0, stream>>>(QT, KTg, Vb, AOT);
    k_out<<<dim3(64, 8, 2), dim3(256), 0, stream>>>(Wb + 196608, bst + 768, AOT,
                                                    (float*)d_out, x);
}

// Round 10
// 146.736 us; speedup vs baseline: 1.1817x; 1.1817x over previous
//
#include <hip/hip_runtime.h>

typedef unsigned short us;
typedef unsigned int uns;
typedef __attribute__((ext_vector_type(8))) short short8;
typedef __attribute__((ext_vector_type(4))) float floatx4;
typedef __attribute__((ext_vector_type(16))) float floatx16;
typedef __attribute__((ext_vector_type(4))) uns unsx4;

__device__ __forceinline__ us f2b(float f) {
    union { float f; unsigned u; } x; x.f = f;
    unsigned r = x.u + 0x7fffu + ((x.u >> 16) & 1u);
    return (us)(r >> 16);
}
__device__ __forceinline__ uns fbits(float f) {
    union { float f; unsigned u; } x; x.f = f; return x.u;
}
// rounded pack (epilogues)
__device__ __forceinline__ uns pk2(float hi, float lo) {
    return __builtin_amdgcn_perm(fbits(hi) + 0x8000u, fbits(lo) + 0x8000u, 0x07060302u);
}
// truncating pack (hot loop: 1 instr; bias cancels in num/den ratio)
__device__ __forceinline__ uns pk2t(float hi, float lo) {
    return __builtin_amdgcn_perm(fbits(hi), fbits(lo), 0x07060302u);
}
// raw v_exp_f32: no denormal-guard expansion (HW flush-to-zero is what
// softmax wants).
__device__ __forceinline__ float ex2(float x) {
    return __builtin_amdgcn_exp2f(x);
}

#define C_DIM 256
#define N_DIM 4096
#define CN (C_DIM * N_DIM)   // 1048576 per batch
#define CSC (0.17677669529663687f * 1.4426950408889634f)   // 1/sqrt(32)*log2e
#define LROW 264              // padded LDS row stride (us): 256 + 8

// ============================================= K1: GN partials + weight prep
__global__ __launch_bounds__(256) void k_part_prep(
        const float* __restrict__ x, float* __restrict__ part,
        const float* __restrict__ Wq, const float* __restrict__ Wk,
        const float* __restrict__ Wv, const float* __restrict__ Wo,
        const float* __restrict__ bq, const float* __restrict__ bk,
        const float* __restrict__ bv, const float* __restrict__ bo,
        us* __restrict__ Wb, float* __restrict__ bst) {
    const int t = threadIdx.x;
    if (blockIdx.y == 16) {   // prep blocks: fold CSC into Wq/bq
        const int xb = blockIdx.x;
#pragma unroll
        for (int e = 0; e < 4; ++e) {
            int id = e * 16384 + xb * 256 + t;
            Wb[id]          = f2b(Wq[id] * CSC);
            Wb[65536 + id]  = f2b(Wk[id]);
            Wb[131072 + id] = f2b(Wv[id]);
            Wb[196608 + id] = f2b(Wo[id]);
        }
        if (xb == 0) {
            bst[t]       = bq[t] * CSC;
            bst[256 + t] = bk[t];
            bst[512 + t] = bv[t];
            bst[768 + t] = bo[t];
        }
        return;
    }
    const int bg = blockIdx.y, sl = blockIdx.x;
    const float* base = x + (size_t)bg * 131072 + (size_t)sl * 2048 + t * 8;
    float4 a = *(const float4*)base;
    float4 b = *(const float4*)(base + 4);
    float s  = a.x + a.y + a.z + a.w + b.x + b.y + b.z + b.w;
    float ss = a.x*a.x + a.y*a.y + a.z*a.z + a.w*a.w
             + b.x*b.x + b.y*b.y + b.z*b.z + b.w*b.w;
    __shared__ float r1[256], r2[256];
    r1[t] = s; r2[t] = ss;
    __syncthreads();
    for (int off = 128; off > 0; off >>= 1) {
        if (t < off) { r1[t] += r1[t + off]; r2[t] += r2[t + off]; }
        __syncthreads();
    }
    if (t == 0) {
        part[(bg * 64 + sl) * 2]     = r1[0];
        part[(bg * 64 + sl) * 2 + 1] = r2[0];
    }
}

// ============================================= K2: normalize -> XT[z][n][c]
// R7-verified: 1024 blocks (4 waves/SIMD) vs 256 saved ~8 us.
__global__ __launch_bounds__(256) void k_gn_normT(const float* __restrict__ x,
                                                  const float* __restrict__ gamma,
                                                  const float* __restrict__ beta,
                                                  const float* __restrict__ part,
                                                  us* __restrict__ XT) {
    const int t = threadIdx.x, g = blockIdx.y, z = blockIdx.z;
    const int nb = blockIdx.x & 15, c8 = blockIdx.x >> 4;
    const int bg = z * 8 + g;
    __shared__ float scs[32], offs[32], mv[2];
    if (t < 64) {
        float s  = part[(bg * 64 + t) * 2];
        float ss = part[(bg * 64 + t) * 2 + 1];
#pragma unroll
        for (int off = 1; off < 64; off <<= 1) {
            s  += __shfl_xor(s, off, 64);
            ss += __shfl_xor(ss, off, 64);
        }
        if (t == 0) {
            const float inv = 1.f / 131072.f;
            float mean = s * inv;
            float var  = ss * inv - mean * mean;
            mv[0] = mean; mv[1] = rsqrtf(var + 1e-5f);
        }
    }
    __syncthreads();
    if (t < 32) {
        float sc = mv[1] * gamma[g * 32 + t];
        scs[t]  = sc;
        offs[t] = beta[g * 32 + t] - mv[0] * sc;
    }
    __syncthreads();
    const int n = nb * 256 + t;
    const float* xp = x + ((size_t)z * 256 + g * 32) * N_DIM + n;
    us* op = XT + ((size_t)z * N_DIM + n) * 256 + g * 32;
    short8 o;
#pragma unroll
    for (int i = 0; i < 8; ++i) {
        int c = c8 * 8 + i;
        float v = xp[(size_t)c * N_DIM];
        o[i] = (short)f2b(v * scs[c] + offs[c]);
    }
    *(short8*)(op + c8 * 8) = o;
}

// ============================================= K3: QKV GEMM (LDS-staged)
// R9 theory: the no-LDS form gathered 16 512B-strided lines per operand
// load (the exact pre-R4 attn pathology, ~2048 line-requests/block).
// Now: A-tile (W rows) and B-tile (XT rows) are CONTIGUOUS 32 KB -> stage
// coalesced into padded LDS (stride 264 us: banks 4*(row+slot) mod 32,
// even 2-way, zero-VALU addressing). K=256 fits whole -> one barrier,
// then a barrier-free fully-unrolled MFMA loop fed from LDS.
__global__ __launch_bounds__(256) void k_qkv(const us* __restrict__ W,
                                             const float* __restrict__ bias,
                                             const us* __restrict__ XT,
                                             us* __restrict__ QT,
                                             us* __restrict__ KTg,
                                             us* __restrict__ Vb) {
    __shared__ __attribute__((aligned(16))) us As[64 * LROW];
    __shared__ __attribute__((aligned(16))) us Bs[64 * LROW];
    const int t = threadIdx.x;
    const int n0 = blockIdx.x * 64, m0 = blockIdx.y * 64, z = blockIdx.z;
    const int l = t & 63, w = t >> 6, l15 = l & 15, quad = l >> 4;
    const int wm = m0 + (w >> 1) * 32, wn = n0 + (w & 1) * 32;

    // ---- stage A+B (each 32 KB contiguous) ----
    {
        const us* Ag = W + (size_t)m0 * 256;
        const us* Bg = XT + ((size_t)z * N_DIM + n0) * 256;
        int4 av[8], bv[8];
#pragma unroll
        for (int i = 0; i < 8; ++i) {
            av[i] = *(const int4*)(Ag + (size_t)i * 2048 + t * 8);
            bv[i] = *(const int4*)(Bg + (size_t)i * 2048 + t * 8);
        }
        const int r0 = t >> 5, s0 = t & 31;
#pragma unroll
        for (int i = 0; i < 8; ++i) {
            *(int4*)(As + (size_t)(i * 8 + r0) * LROW + s0 * 8) = av[i];
            *(int4*)(Bs + (size_t)(i * 8 + r0) * LROW + s0 * 8) = bv[i];
        }
    }
    __syncthreads();

    const int ra = (w >> 1) * 32 + l15, rb = (w & 1) * 32 + l15;
    const us* pa0 = As + (size_t)ra * LROW + quad * 8;
    const us* pa1 = As + (size_t)(ra + 16) * LROW + quad * 8;
    const us* pb0 = Bs + (size_t)rb * LROW + quad * 8;
    const us* pb1 = Bs + (size_t)(rb + 16) * LROW + quad * 8;

    floatx4 acc[2][2] = {};
#pragma unroll
    for (int k0 = 0; k0 < 256; k0 += 32) {
        short8 a0 = *(const short8*)(pa0 + k0);
        short8 a1 = *(const short8*)(pa1 + k0);
        short8 b0 = *(const short8*)(pb0 + k0);
        short8 b1 = *(const short8*)(pb1 + k0);
        acc[0][0] = __builtin_amdgcn_mfma_f32_16x16x32_bf16(a0, b0, acc[0][0], 0, 0, 0);
        acc[0][1] = __builtin_amdgcn_mfma_f32_16x16x32_bf16(a0, b1, acc[0][1], 0, 0, 0);
        acc[1][0] = __builtin_amdgcn_mfma_f32_16x16x32_bf16(a1, b0, acc[1][0], 0, 0, 0);
        acc[1][1] = __builtin_amdgcn_mfma_f32_16x16x32_bf16(a1, b1, acc[1][1], 0, 0, 0);
    }

    if (blockIdx.y < 8) {   // Q or K: packed-transposed [bh][n][32] stores
        us* Dst = (blockIdx.y < 4) ? QT : KTg;
        const int h = (wm >> 5) & 7, bh = z * 8 + h;
#pragma unroll
        for (int mt = 0; mt < 2; ++mt) {
            float b0v = bias[wm + mt * 16 + quad * 4 + 0];
            float b1v = bias[wm + mt * 16 + quad * 4 + 1];
            float b2v = bias[wm + mt * 16 + quad * 4 + 2];
            float b3v = bias[wm + mt * 16 + quad * 4 + 3];
            const int d0 = mt * 16 + quad * 4;
#pragma unroll
            for (int nt = 0; nt < 2; ++nt) {
                int col = wn + nt * 16 + l15;
                uint2 pw;
                pw.x = pk2(acc[mt][nt][1] + b1v, acc[mt][nt][0] + b0v);
                pw.y = pk2(acc[mt][nt][3] + b3v, acc[mt][nt][2] + b2v);
                *(uint2*)(Dst + ((size_t)bh * N_DIM + col) * 32 + d0) = pw;
            }
        }
    } else {                // V rows: natural [c][n]
#pragma unroll
        for (int mt = 0; mt < 2; ++mt)
#pragma unroll
            for (int nt = 0; nt < 2; ++nt)
#pragma unroll
                for (int r = 0; r < 4; ++r) {
                    int row = wm + mt * 16 + quad * 4 + r;
                    int col = wn + nt * 16 + l15;
                    Vb[((size_t)z * 256 + (row - 512)) * N_DIM + col] =
                        f2b(acc[mt][nt][r] + bias[row]);
                }
    }
}

// ============================================= K4: attention
// Block = 512 threads = 8 waves = 4 q-tiles(32q) x 2 key-halves(2048).
// R8-proven config (53.0 us). R9 lesson: 1024-thr 4-way split raised
// occupancy 32->38 but LOST 3.8 us (16-wave barrier lockstep + shorter
// loop + 3-partial epilogue). R7 lesson: no accumulator ILP (spill).
// This geometry is attn's local optimum -- frozen.
__device__ __forceinline__ floatx16 mfma32(short8 a, short8 b, floatx16 c) {
    return __builtin_amdgcn_mfma_f32_32x32x16_bf16(a, b, c, 0, 0, 0);
}
// exp2 + truncate-pack one 32-key tile's scores, then half-swap into the
// two k=16 B-fragments (v_permlane32_swap_b32: vdst.hi <-> vsrc.lo).
__device__ __forceinline__ void mkfrag(const floatx16& s, short8& p1, short8& p2) {
    uns d0 = pk2t(ex2(s[1]),  ex2(s[0]));
    uns d1 = pk2t(ex2(s[3]),  ex2(s[2]));
    uns d2 = pk2t(ex2(s[5]),  ex2(s[4]));
    uns d3 = pk2t(ex2(s[7]),  ex2(s[6]));
    uns d4 = pk2t(ex2(s[9]),  ex2(s[8]));
    uns d5 = pk2t(ex2(s[11]), ex2(s[10]));
    uns d6 = pk2t(ex2(s[13]), ex2(s[12]));
    uns d7 = pk2t(ex2(s[15]), ex2(s[14]));
    asm volatile("v_permlane32_swap_b32 %0, %1" : "+v"(d0), "+v"(d2));
    asm volatile("v_permlane32_swap_b32 %0, %1" : "+v"(d1), "+v"(d3));
    asm volatile("v_permlane32_swap_b32 %0, %1" : "+v"(d4), "+v"(d6));
    asm volatile("v_permlane32_swap_b32 %0, %1" : "+v"(d5), "+v"(d7));
    unsx4 u1 = {d0, d1, d2, d3};
    unsx4 u2 = {d4, d5, d6, d7};
    p1 = __builtin_bit_cast(short8, u1);
    p2 = __builtin_bit_cast(short8, u2);
}

__global__ __launch_bounds__(512, 4) void k_attn(const us* __restrict__ QT,
                                                 const us* __restrict__ KTg,
                                                 const us* __restrict__ Vb,
                                                 us* __restrict__ AOT) {
    // layout: K half-tiles [buf][kh] at 0, V half-tiles [buf][kh] at +8192 us
    __shared__ __attribute__((aligned(16))) us SM[16384];   // 32 KB
    us* Kbase = SM;
    us* Vbase = SM + 8192;
    const int t = threadIdx.x;
    const int l = t & 63, w = t >> 6, hf = l >> 5, k31 = l & 31;
    const int sw = w & 3, kh = w >> 2;          // q-tile role, key-half role
    const int bh = blockIdx.y, z = bh >> 3, hd = bh & 7;
    const us* KTp = KTg + (size_t)bh * N_DIM * 32;
    const us* Vp  = Vb  + ((size_t)z * 256 + hd * 32) * N_DIM;
    const int q0 = blockIdx.x * 128 + sw * 32;

    // Q B-frags: n=q=lane&31, k=d=8*hf+j (bq1: d 0-15, bq2: d 16-31)
    const us* qb = QT + ((size_t)bh * N_DIM + q0 + k31) * 32 + hf * 8;
    short8 bq1 = *(const short8*)qb;
    short8 bq2 = *(const short8*)(qb + 16);
    short8 ones;
#pragma unroll
    for (int j = 0; j < 8; ++j) ones[j] = (short)0x3F80;   // bf16 1.0

    floatx16 o  = (floatx16)0.0f;
    floatx16 dn = (floatx16)0.0f;

    // ---- cooperative staging constants: wave stages its own half's tile ----
    const int krow = sw * 16 + (l >> 2), kslot = l & 3;
    const int kxs  = kslot ^ ((l >> 3) & 3);          // == kslot ^ ((krow>>1)&3)
    const us* kgs  = KTp + (size_t)(kh * 2048 + krow) * 32 + kslot * 8;
    us*       kds  = Kbase + kh * 2048 + krow * 32 + kxs * 8;
    const int vrow = sw * 8 + (l >> 3), vslot = l & 7;
    const int vxs  = vslot ^ ((l >> 3) & 7);          // == vslot ^ (vrow&7)
    const us* vgs  = Vp + (size_t)vrow * N_DIM + kh * 2048 + vslot * 8;
    us*       vds  = Vbase + kh * 2048 + vrow * 64 + vxs * 8;

    // ---- swizzled frag-read pointers (own half slice) ----
    const int kf = (k31 >> 1) & 3;
    const us* ka0p = Kbase + kh * 2048 + k31 * 32 + ((hf)     ^ kf) * 8;
    const us* ka1p = Kbase + kh * 2048 + k31 * 32 + ((2 + hf) ^ kf) * 8;
    const int vf = k31 & 7;
    const us* vp0 = Vbase + kh * 2048 + k31 * 64 + ((0 + hf) ^ vf) * 8;
    const us* vp1 = Vbase + kh * 2048 + k31 * 64 + ((2 + hf) ^ vf) * 8;
    const us* vp2 = Vbase + kh * 2048 + k31 * 64 + ((4 + hf) ^ vf) * 8;
    const us* vp3 = Vbase + kh * 2048 + k31 * 64 + ((6 + hf) ^ vf) * 8;

    // prologue: stage tile 0 into buf 0
    {
        int4 gk = *(const int4*)kgs;
        int4 gv = *(const int4*)vgs;
        *(int4*)kds = gk;
        *(int4*)vds = gv;
    }
    __syncthreads();
    int cur = 0;

    for (int m0 = 0; m0 < 2048; m0 += 64) {
        // issue next-tile global loads (consumed by ds_write at loop tail)
        const int mnext = (m0 + 64) & 2047;
        int4 ngk = *(const int4*)(kgs + (size_t)mnext * 32);
        int4 ngv = *(const int4*)(vgs + mnext);

        const int bo = cur * 4096;           // [buf] stride = 2 half-tiles
        short8 ka0 = *(const short8*)(ka0p + bo);          // keys 0-31, d 0-15
        short8 ka1 = *(const short8*)(ka1p + bo);          // keys 0-31, d 16-31
        short8 kb0 = *(const short8*)(ka0p + bo + 1024);   // keys 32-63
        short8 kb1 = *(const short8*)(ka1p + bo + 1024);
        short8 v0  = *(const short8*)(vp0 + bo);           // keys  0-15
        short8 v1  = *(const short8*)(vp1 + bo);           // keys 16-31
        short8 v2  = *(const short8*)(vp2 + bo);           // keys 32-47
        short8 v3  = *(const short8*)(vp3 + bo);           // keys 48-63

        floatx16 s0 = (floatx16)0.0f, s1 = (floatx16)0.0f;
        s0 = mfma32(ka0, bq1, s0);
        s0 = mfma32(ka1, bq2, s0);
        s1 = mfma32(kb0, bq1, s1);
        s1 = mfma32(kb1, bq2, s1);

        short8 p1, p2, p3, p4;
        mkfrag(s0, p1, p2);
        mkfrag(s1, p3, p4);

        o  = mfma32(v0, p1, o);   dn = mfma32(ones, p1, dn);
        o  = mfma32(v1, p2, o);   dn = mfma32(ones, p2, dn);
        o  = mfma32(v2, p3, o);   dn = mfma32(ones, p3, dn);
        o  = mfma32(v3, p4, o);   dn = mfma32(ones, p4, dn);

        // write staged tile into buf[cur^1]; barrier publishes it
        *(int4*)(kds + (cur ^ 1) * 4096) = ngk;
        *(int4*)(vds + (cur ^ 1) * 4096) = ngv;
        __syncthreads();
        cur ^= 1;
    }

    // -------- combine key-half partials: waves (sw, sw+4) ----------
    // scratch reuses SM (20 KB of 32 KB); stride 20 dwords (16B-aligned).
    float* sc = (float*)SM;
    if (kh) {
        float* dst = sc + (size_t)(sw * 64 + l) * 20;
        *(floatx4*)(dst + 0)  = ((const floatx4*)&o)[0];
        *(floatx4*)(dst + 4)  = ((const floatx4*)&o)[1];
        *(floatx4*)(dst + 8)  = ((const floatx4*)&o)[2];
        *(floatx4*)(dst + 12) = ((const floatx4*)&o)[3];
        dst[16] = dn[0];
    }
    __syncthreads();
    if (!kh) {
        const float* src = sc + (size_t)(sw * 64 + l) * 20;
        floatx4 a0 = *(const floatx4*)(src + 0);
        floatx4 a1 = *(const floatx4*)(src + 4);
        floatx4 a2 = *(const floatx4*)(src + 8);
        floatx4 a3 = *(const floatx4*)(src + 12);
        const float dtot = dn[0] + src[16];

        float ov[16];
#pragma unroll
        for (int i = 0; i < 4; ++i) {
            ov[i]      = o[i]      + a0[i];
            ov[4 + i]  = o[4 + i]  + a1[i];
            ov[8 + i]  = o[8 + i]  + a2[i];
            ov[12 + i] = o[12 + i] + a3[i];
        }

        // O[d][q]: d=(reg&3)+8*(reg>>2)+4*hf, q=q0+k31
        const float inv = 1.f / dtot;
        const int q = q0 + k31;
        us* op = AOT + ((size_t)z * N_DIM + q) * 256 + hd * 32 + hf * 4;
#pragma unroll
        for (int g = 0; g < 4; ++g) {
            uint2 u;
            u.x = pk2(ov[4 * g + 1] * inv, ov[4 * g + 0] * inv);
            u.y = pk2(ov[4 * g + 3] * inv, ov[4 * g + 2] * inv);
            *(uint2*)(op + 8 * g) = u;
        }
    }
}

// ============================================= K5: output GEMM (LDS-staged)
// Same R4-pattern LDS staging as k_qkv; epilogue fp32 + resid unchanged.
__global__ __launch_bounds__(256) void k_out(const us* __restrict__ W,
                                             const float* __restrict__ bias,
                                             const us* __restrict__ AOT,
                                             float* __restrict__ Out,
                                             const float* __restrict__ resid) {
    __shared__ __attribute__((aligned(16))) us As[64 * LROW];
    __shared__ __attribute__((aligned(16))) us Bs[64 * LROW];
    const int t = threadIdx.x;
    const int n0 = blockIdx.x * 64, m0 = blockIdx.y * 64, z = blockIdx.z;
    const int l = t & 63, w = t >> 6, l15 = l & 15, quad = l >> 4;
    const int wm = m0 + (w >> 1) * 32, wn = n0 + (w & 1) * 32;

    {
        const us* Ag = W + (size_t)m0 * 256;
        const us* Bg = AOT + ((size_t)z * N_DIM + n0) * 256;
        int4 av[8], bv[8];
#pragma unroll
        for (int i = 0; i < 8; ++i) {
            av[i] = *(const int4*)(Ag + (size_t)i * 2048 + t * 8);
            bv[i] = *(const int4*)(Bg + (size_t)i * 2048 + t * 8);
        }
        const int r0 = t >> 5, s0 = t & 31;
#pragma unroll
        for (int i = 0; i < 8; ++i) {
            *(int4*)(As + (size_t)(i * 8 + r0) * LROW + s0 * 8) = av[i];
            *(int4*)(Bs + (size_t)(i * 8 + r0) * LROW + s0 * 8) = bv[i];
        }
    }
    __syncthreads();

    const int ra = (w >> 1) * 32 + l15, rb = (w & 1) * 32 + l15;
    const us* pa0 = As + (size_t)ra * LROW + quad * 8;
    const us* pa1 = As + (size_t)(ra + 16) * LROW + quad * 8;
    const us* pb0 = Bs + (size_t)rb * LROW + quad * 8;
    const us* pb1 = Bs + (size_t)(rb + 16) * LROW + quad * 8;

    floatx4 acc[2][2] = {};
#pragma unroll
    for (int k0 = 0; k0 < 256; k0 += 32) {
        short8 a0 = *(const short8*)(pa0 + k0);
        short8 a1 = *(const short8*)(pa1 + k0);
        short8 b0 = *(const short8*)(pb0 + k0);
        short8 b1 = *(const short8*)(pb1 + k0);
        acc[0][0] = __builtin_amdgcn_mfma_f32_16x16x32_bf16(a0, b0, acc[0][0], 0, 0, 0);
        acc[0][1] = __builtin_amdgcn_mfma_f32_16x16x32_bf16(a0, b1, acc[0][1], 0, 0, 0);
        acc[1][0] = __builtin_amdgcn_mfma_f32_16x16x32_bf16(a1, b0, acc[1][0], 0, 0, 0);
        acc[1][1] = __builtin_amdgcn_mfma_f32_16x16x32_bf16(a1, b1, acc[1][1], 0, 0, 0);
    }

#pragma unroll
    for (int mt = 0; mt < 2; ++mt)
#pragma unroll
        for (int nt = 0; nt < 2; ++nt)
#pragma unroll
            for (int r = 0; r < 4; ++r) {
                int row = wm + mt * 16 + quad * 4 + r;
                int col = wn + nt * 16 + l15;
                size_t oidx = ((size_t)z * 256 + row) * N_DIM + col;
                Out[oidx] = acc[mt][nt][r] + bias[row] + resid[oidx];
            }
}

// ============================================= launch
extern "C" void kernel_launch(void* const* d_in, const int* in_sizes, int n_in,
                              void* d_out, int out_size, void* d_ws, size_t ws_size,
                              hipStream_t stream) {
    (void)in_sizes; (void)n_in; (void)out_size; (void)ws_size;
    const float* x     = (const float*)d_in[0];
    const float* gamma = (const float*)d_in[1];
    const float* beta  = (const float*)d_in[2];
    const float* Wq = (const float*)d_in[3]; const float* bq = (const float*)d_in[4];
    const float* Wk = (const float*)d_in[5]; const float* bk = (const float*)d_in[6];
    const float* Wv = (const float*)d_in[7]; const float* bv = (const float*)d_in[8];
    const float* Wo = (const float*)d_in[9]; const float* bo = (const float*)d_in[10];

    float* part = (float*)d_ws;                                  // 2048 f
    us*    Wb   = (us*)((char*)d_ws + 16384);                    // 512 KB
    float* bst  = (float*)((char*)d_ws + 16384 + 524288);        // 4 KB
    us*    XT   = (us*)((char*)d_ws + 16384 + 524288 + 4096);    // 4 MB
    us*    QT   = XT + 2 * CN;                                   // [16][4096][32] 4 MB
    us*    AOT  = QT + 2 * CN;                                   // 4 MB
    us*    Vb   = (us*)d_out;                                    // d_out front 4 MB
    us*    KTg  = (us*)d_out + 2 * CN;                           // d_out back 4 MB

    k_part_prep<<<dim3(64, 17), dim3(256), 0, stream>>>(x, part, Wq, Wk, Wv, Wo,
                                                        bq, bk, bv, bo, Wb, bst);
    k_gn_normT<<<dim3(64, 8, 2), dim3(256), 0, stream>>>(x, gamma, beta, part, XT);
    k_qkv<<<dim3(64, 12, 2), dim3(256), 0, stream>>>(Wb, bst, XT, QT, KTg, Vb);
    k_attn<<<dim3(32, 16), dim3(512), 0, stream>>>(QT, KTg, Vb, AOT);
    k_out<<<dim3(64, 4, 2), dim3(256), 0, stream>>>(Wb + 196608, bst + 768, AOT,
                                                    (float*)d_out, x);
}